// Round 10
// baseline (4244.382 us; speedup 1.0000x reference)
//
#include <hip/hip_runtime.h>
#include <cstdint>

typedef unsigned long long u64;
typedef float v2f __attribute__((ext_vector_type(2)));

static constexpr int BB = 2;
static constexpr int NN = 16384;
static constexpr int SS = 4096;

// single-step DPP max: compiler folds the DPP into v_max_u32 (1 instr/step)
template <int CTRL>
__device__ __forceinline__ unsigned umax_dpp(unsigned v) {
  unsigned s = (unsigned)__builtin_amdgcn_update_dpp(0, (int)v, CTRL, 0xF, 0xF, true);
  return v > s ? v : s;
}

// u32 max-reduce across the wave, broadcast via readlane(63). Identity 0.
__device__ __forceinline__ unsigned wave_umax_bcast(unsigned v) {
  v = umax_dpp<0x111>(v);  // row_shr:1
  v = umax_dpp<0x112>(v);  // row_shr:2
  v = umax_dpp<0x114>(v);  // row_shr:4
  v = umax_dpp<0x118>(v);  // row_shr:8
  v = umax_dpp<0x142>(v);  // row_bcast:15
  v = umax_dpp<0x143>(v);  // row_bcast:31
  return (unsigned)__builtin_amdgcn_readlane((int)v, 63);
}

// u32 max-reduce over a 16-element row (values replicated per row via lane&15)
__device__ __forceinline__ unsigned row16_umax(unsigned v) {
  v = umax_dpp<0x128>(v);  // row_ror:8
  v = umax_dpp<0x124>(v);  // row_ror:4
  v = umax_dpp<0x122>(v);  // row_ror:2
  v = umax_dpp<0x121>(v);  // row_ror:1
  return v;
}

__device__ __forceinline__ v2f emin2(v2f a, v2f b) {
  v2f r; r[0] = fminf(a[0], b[0]); r[1] = fminf(a[1], b[1]); return r;
}
__device__ __forceinline__ v2f emax2(v2f a, v2f b) {
  v2f r; r[0] = fmaxf(a[0], b[0]); r[1] = fmaxf(a[1], b[1]); return r;
}

// spread 4 bits: bit k -> bit 3k (for 12-bit Morton)
__device__ __forceinline__ unsigned spread4(unsigned v) {
  return (v & 1u) | ((v & 2u) << 2) | ((v & 4u) << 4) | ((v & 8u) << 6);
}

__device__ __forceinline__ unsigned cell_of(float x, float y, float z) {
  int cx = (int)floorf((x + 4.f) * 2.f);
  int cy = (int)floorf((y + 4.f) * 2.f);
  int cz = (int)floorf((z + 4.f) * 2.f);
  cx = min(max(cx, 0), 15); cy = min(max(cy, 0), 15); cz = min(max(cz, 0), 15);
  return spread4((unsigned)cx) | (spread4((unsigned)cy) << 1) |
         (spread4((unsigned)cz) << 2);
}

// ---------------------------------------------------------------------------
// Counting sort by 12-bit Morton cell -> spts float4 {x,y,z,bits(orig_idx)}.
// Also writes x4 = original-order float4 copy (uniform 16B winner-coord
// s_load in fps). Within-cell scatter order is atomic-nondeterministic but
// the FPS output is invariant to it.
// ---------------------------------------------------------------------------
__global__ __launch_bounds__(1024) void sort_kernel(
    const float* __restrict__ xyz, float4* __restrict__ spts,
    float4* __restrict__ x4)
{
  const int b = blockIdx.x;
  const float* X = xyz + (size_t)b * NN * 3;
  float4* SP = spts + (size_t)b * NN;
  float4* XO = x4 + (size_t)b * NN;
  const int t = threadIdx.x;
  const int lane = t & 63, wid = t >> 6;

  __shared__ unsigned h[4096];
  __shared__ unsigned wtot[16];
  for (int j = t; j < 4096; j += 1024) h[j] = 0;
  __syncthreads();

  for (int i = 0; i < 16; ++i) {
    int p = i * 1024 + t;
    float x = X[p * 3 + 0], y = X[p * 3 + 1], z = X[p * 3 + 2];
    XO[p] = make_float4(x, y, z, 0.f);
    atomicAdd(&h[cell_of(x, y, z)], 1u);
  }
  __syncthreads();

  unsigned a0 = h[4 * t], a1 = h[4 * t + 1], a2 = h[4 * t + 2], a3 = h[4 * t + 3];
  unsigned s4 = a0 + a1 + a2 + a3;
  unsigned incl = s4;
  for (int off = 1; off < 64; off <<= 1) {
    unsigned v = (unsigned)__shfl_up((int)incl, off);
    if (lane >= off) incl += v;
  }
  if (lane == 63) wtot[wid] = incl;
  __syncthreads();
  if (t == 0) {
    unsigned run = 0;
    for (int j = 0; j < 16; ++j) { unsigned tm = wtot[j]; wtot[j] = run; run += tm; }
  }
  __syncthreads();
  unsigned ex = wtot[wid] + (incl - s4);
  h[4 * t] = ex; h[4 * t + 1] = ex + a0;
  h[4 * t + 2] = ex + a0 + a1; h[4 * t + 3] = ex + a0 + a1 + a2;
  __syncthreads();

  for (int i = 0; i < 16; ++i) {
    int p = i * 1024 + t;
    float x = X[p * 3 + 0], y = X[p * 3 + 1], z = X[p * 3 + 2];
    unsigned pos = atomicAdd(&h[cell_of(x, y, z)], 1u);
    SP[pos] = make_float4(x, y, z, __int_as_float(p));
  }
}

// ---------------------------------------------------------------------------
// FPS: R9 structure (1024 thr / 16 waves, wave-granularity exact pruning,
// register-resident packed-v2f coords/dists) with a slimmed fixed tail:
// - cross-wave reduce split into two u32 4-step DPP umax chains (dist bits,
//   then (bits==blockmax)?~idx:0) instead of a u64 compare-swap chain
// - all DPP reduce steps expressed as umax(v, dpp(v)) -> single v_max_u32
// - skip test uses fmax(fmax(a,b),0) -> v_max3_f32
// Exactness: fp contract off (packed rounding == scalar == numpy); dist^2>=0
// so bit order == float order; max(~idx) == min orig idx == numpy first-index
// tie-break; skip margin (1-2^-16) covers both roundings -> skips are no-ops.
// Output invariant to sort nondeterminism.
// ---------------------------------------------------------------------------
__global__ __launch_bounds__(1024) void fps_kernel(
    const float4* __restrict__ x4, const float4* __restrict__ spts,
    float* __restrict__ new_xyz)
{
#pragma clang fp contract(off)
  const int b = blockIdx.x;
  const float4* XO = x4 + (size_t)b * NN;
  float* NX = new_xyz + (size_t)b * SS * 3;
  const int t = threadIdx.x;
  const int lane = t & 63, wid = t >> 6;
  const float4* WP = spts + (size_t)b * NN + wid * 1024;

  v2f xp0, xp1, xp2, xp3, xp4, xp5, xp6, xp7;
  v2f yp0, yp1, yp2, yp3, yp4, yp5, yp6, yp7;
  v2f zp0, zp1, zp2, zp3, zp4, zp5, zp6, zp7;
  v2f dp0, dp1, dp2, dp3, dp4, dp5, dp6, dp7;
  unsigned na0, na1, na2, na3, na4, na5, na6, na7;
  unsigned nb0, nb1, nb2, nb3, nb4, nb5, nb6, nb7;
#define LOADV(v)                                                              \
  {                                                                           \
    float4 Pa = WP[(2 * (v)) * 64 + lane];                                    \
    float4 Pb = WP[(2 * (v) + 1) * 64 + lane];                                \
    xp##v[0] = Pa.x; xp##v[1] = Pb.x;                                         \
    yp##v[0] = Pa.y; yp##v[1] = Pb.y;                                         \
    zp##v[0] = Pa.z; zp##v[1] = Pb.z;                                         \
    na##v = ~__float_as_uint(Pa.w); nb##v = ~__float_as_uint(Pb.w);           \
    dp##v[0] = 1e10f; dp##v[1] = 1e10f;                                       \
  }
  LOADV(0) LOADV(1) LOADV(2) LOADV(3) LOADV(4) LOADV(5) LOADV(6) LOADV(7)
#undef LOADV

  // wave bbox (uniform across the wave after shuffles)
  float bnx, bny, bnz, bxx, bxy, bxz;
  {
    v2f nx2 = emin2(emin2(emin2(xp0, xp1), emin2(xp2, xp3)),
                    emin2(emin2(xp4, xp5), emin2(xp6, xp7)));
    v2f xx2 = emax2(emax2(emax2(xp0, xp1), emax2(xp2, xp3)),
                    emax2(emax2(xp4, xp5), emax2(xp6, xp7)));
    v2f ny2 = emin2(emin2(emin2(yp0, yp1), emin2(yp2, yp3)),
                    emin2(emin2(yp4, yp5), emin2(yp6, yp7)));
    v2f xy2 = emax2(emax2(emax2(yp0, yp1), emax2(yp2, yp3)),
                    emax2(emax2(yp4, yp5), emax2(yp6, yp7)));
    v2f nz2 = emin2(emin2(emin2(zp0, zp1), emin2(zp2, zp3)),
                    emin2(emin2(zp4, zp5), emin2(zp6, zp7)));
    v2f xz2 = emax2(emax2(emax2(zp0, zp1), emax2(zp2, zp3)),
                    emax2(emax2(zp4, zp5), emax2(zp6, zp7)));
    bnx = fminf(nx2[0], nx2[1]); bxx = fmaxf(xx2[0], xx2[1]);
    bny = fminf(ny2[0], ny2[1]); bxy = fmaxf(xy2[0], xy2[1]);
    bnz = fminf(nz2[0], nz2[1]); bxz = fmaxf(xz2[0], xz2[1]);
#pragma unroll
    for (int off = 1; off < 64; off <<= 1) {
      bnx = fminf(bnx, __shfl_xor(bnx, off));
      bxx = fmaxf(bxx, __shfl_xor(bxx, off));
      bny = fminf(bny, __shfl_xor(bny, off));
      bxy = fmaxf(bxy, __shfl_xor(bxy, off));
      bnz = fminf(bnz, __shfl_xor(bnz, off));
      bxz = fmaxf(bxz, __shfl_xor(bxz, off));
    }
  }

  // cached wave key: max dist bits + ~orig_idx of the wave winner
  unsigned wmaxb = __float_as_uint(1e10f), wni = 0u;

  __shared__ u64 sp[2][16];
  float qx, qy, qz;
  { float4 q0 = XO[0]; qx = q0.x; qy = q0.y; qz = q0.z; }

  for (int it = 1; it < SS; ++it) {
    if (t == 0) {
      NX[(it - 1) * 3 + 0] = qx;
      NX[(it - 1) * 3 + 1] = qy;
      NX[(it - 1) * 3 + 2] = qz;
    }
    // conservative lower bound of dist^2(q, wave bbox); wave-uniform branch
    float tx = fmaxf(fmaxf(__fsub_rn(bnx, qx), __fsub_rn(qx, bxx)), 0.f);
    float ty = fmaxf(fmaxf(__fsub_rn(bny, qy), __fsub_rn(qy, bxy)), 0.f);
    float tz = fmaxf(fmaxf(__fsub_rn(bnz, qz), __fsub_rn(qz, bxz)), 0.f);
    float lb2 = fmaf(tx, tx, fmaf(ty, ty, __fmul_rn(tz, tz)));
    if (__fmul_rn(lb2, 0.99998474f) < __uint_as_float(wmaxb)) {
      v2f q2x, q2y, q2z;
      q2x[0] = qx; q2x[1] = qx;
      q2y[0] = qy; q2y[1] = qy;
      q2z[0] = qz; q2z[1] = qz;
#define UPDV(v)                                                               \
      {                                                                       \
        v2f dx = xp##v - q2x, dy = yp##v - q2y, dz = zp##v - q2z;             \
        v2f s = (dx * dx + dy * dy) + dz * dz;                                \
        dp##v = emin2(dp##v, s);                                              \
      }
      UPDV(0) UPDV(1) UPDV(2) UPDV(3) UPDV(4) UPDV(5) UPDV(6) UPDV(7)
#undef UPDV
      // phase 1: wave max dist (float-bit order == float order, dist >= 0)
      v2f mall = emax2(emax2(emax2(dp0, dp1), emax2(dp2, dp3)),
                       emax2(emax2(dp4, dp5), emax2(dp6, dp7)));
      unsigned mm = wave_umax_bcast(__float_as_uint(fmaxf(mall[0], mall[1])));
      // phase 2: tie-exact winner extraction (max ~idx == min orig idx)
      unsigned c = 0u;
#define CSEL(v)                                                               \
      c = max(c, (__float_as_uint(dp##v[0]) == mm) ? na##v : 0u);             \
      c = max(c, (__float_as_uint(dp##v[1]) == mm) ? nb##v : 0u);
      CSEL(0) CSEL(1) CSEL(2) CSEL(3) CSEL(4) CSEL(5) CSEL(6) CSEL(7)
#undef CSEL
      wni = wave_umax_bcast(c);
      wmaxb = mm;
    }
    // publish cached key (always; double-buffered, single barrier)
    const int pb = it & 1;
    if (lane == 0) sp[pb][wid] = ((u64)wmaxb << 32) | (u64)wni;
    __syncthreads();
    u64 kk = sp[pb][lane & 15];
    unsigned kd = (unsigned)(kk >> 32);      // dist bits of wave lane&15
    unsigned ki = (unsigned)kk;              // ~idx of wave lane&15
    unsigned bm = row16_umax(kd);            // block max dist bits
    unsigned cand = (kd == bm) ? ki : 0u;    // candidates at block max
    cand = row16_umax(cand);                 // max ~idx -> min orig idx
    unsigned widx = ~cand;
    widx = (unsigned)__builtin_amdgcn_readfirstlane((int)widx);
    float4 q = XO[widx];
    qx = q.x; qy = q.y; qz = q.z;
  }
  if (t == 0) {
    NX[(SS - 1) * 3 + 0] = qx;
    NX[(SS - 1) * 3 + 1] = qy;
    NX[(SS - 1) * 3 + 2] = qz;
  }
}

// ---------------------------------------------------------------------------
// Ball query: one 64-lane wave per query point. Emits the first NS in-radius
// point indices in ascending order (matches reference top_k(-keys) trick),
// pads with the first hit.
// ---------------------------------------------------------------------------
template <int NS>
__global__ __launch_bounds__(256) void ballq_kernel(
    const float* __restrict__ xyz, const float* __restrict__ new_xyz,
    int* __restrict__ out, float r2)
{
  const int q = blockIdx.x * 4 + (threadIdx.x >> 6);
  const int lane = threadIdx.x & 63;
  const int b = q >> 12;  // q / SS
  const float* X = xyz + (size_t)b * NN * 3;
  const float cx = new_xyz[q * 3 + 0];
  const float cy = new_xyz[q * 3 + 1];
  const float cz = new_xyz[q * 3 + 2];
  int* o = out + (size_t)q * NS;
  int base = 0;
  int firstIdx = 0x7fffffff;
  for (int c0 = 0; c0 < NN; c0 += 64) {
    const int p = c0 + lane;
    float dx = __fsub_rn(cx, X[p * 3 + 0]);
    float dy = __fsub_rn(cy, X[p * 3 + 1]);
    float dz = __fsub_rn(cz, X[p * 3 + 2]);
    float d2 = __fadd_rn(__fadd_rn(__fmul_rn(dx, dx), __fmul_rn(dy, dy)),
                         __fmul_rn(dz, dz));
    const bool inb = d2 < r2;
    const unsigned long long mm = __ballot(inb);
    if (inb) {
      int rank = base + (int)__popcll(mm & ((1ull << lane) - 1ull));
      if (rank < NS) {
        o[rank] = p;
        if (rank == 0) firstIdx = p;
      }
    }
    base += (int)__popcll(mm);
    if (base >= NS) break;
  }
#pragma unroll
  for (int off = 32; off >= 1; off >>= 1)
    firstIdx = min(firstIdx, __shfl_xor(firstIdx, off));
  for (int r = base + lane; r < NS; r += 64) o[r] = firstIdx;
}

// ---------------------------------------------------------------------------
// Grouping + 3-layer MLP + max over samples. One thread per (query, sample).
// ---------------------------------------------------------------------------
template <int NS, int C1, int C2, int C3>
__global__ __launch_bounds__(256) void group_mlp_kernel(
    const float* __restrict__ xyz, const float* __restrict__ feat,
    const float* __restrict__ new_xyz, const int* __restrict__ idx,
    const float* __restrict__ w0, const float* __restrict__ b0,
    const float* __restrict__ w1, const float* __restrict__ b1,
    const float* __restrict__ w2, const float* __restrict__ b2,
    float* __restrict__ pf, int chOff)
{
  constexpr int QPB = 256 / NS;
  const int q = blockIdx.x * QPB + (int)(threadIdx.x / NS);
  const int k = (int)(threadIdx.x % NS);
  const int b = q >> 12;
  const int s = q & (SS - 1);
  const float* X = xyz + (size_t)b * NN * 3;
  const float* F = feat + (size_t)b * 6 * NN;
  const int p = idx[(size_t)q * NS + k];

  float in[9];
  in[0] = X[p * 3 + 0] - new_xyz[q * 3 + 0];
  in[1] = X[p * 3 + 1] - new_xyz[q * 3 + 1];
  in[2] = X[p * 3 + 2] - new_xyz[q * 3 + 2];
#pragma unroll
  for (int c = 0; c < 6; ++c) in[3 + c] = F[c * NN + p];

  float h1[C1];
#pragma unroll
  for (int oc = 0; oc < C1; ++oc) {
    float a = b0[oc];
#pragma unroll
    for (int c = 0; c < 9; ++c) a = fmaf(w0[oc * 9 + c], in[c], a);
    h1[oc] = fmaxf(a, 0.f);
  }
  float h2[C2];
#pragma unroll
  for (int oc = 0; oc < C2; ++oc) {
    float a = b1[oc];
#pragma unroll
    for (int c = 0; c < C1; ++c) a = fmaf(w1[oc * C1 + c], h1[c], a);
    h2[oc] = fmaxf(a, 0.f);
  }
#pragma unroll
  for (int oc = 0; oc < C3; ++oc) {
    float a = b2[oc];
#pragma unroll
    for (int c = 0; c < C2; ++c) a = fmaf(w2[oc * C2 + c], h2[c], a);
    float v = fmaxf(a, 0.f);
#pragma unroll
    for (int off = NS / 2; off >= 1; off >>= 1)
      v = fmaxf(v, __shfl_xor(v, off));
    if (k == 0) pf[(((size_t)b * 96) + chOff + oc) * SS + s] = v;
  }
}

// ---------------------------------------------------------------------------
// Image branch + attention + fusion, 32-column LDS tiles.
// ---------------------------------------------------------------------------
__global__ __launch_bounds__(256) void img_fuse_kernel(
    const float* __restrict__ imgf, const float* __restrict__ pf,
    const float* __restrict__ w_img, const float* __restrict__ b_img,
    const float* __restrict__ w_fc2, const float* __restrict__ b_fc2,
    const float* __restrict__ w_fc3, const float* __restrict__ b_fc3,
    const float* __restrict__ w_pc, const float* __restrict__ b_pc,
    const float* __restrict__ w_fuse, const float* __restrict__ b_fuse,
    float* __restrict__ out)
{
  constexpr int TS = 32;
  __shared__ float x_lds[64][TS];
  __shared__ float img_lds[96][TS];
  __shared__ float ri_lds[24][TS];
  __shared__ float att_lds[TS];
  __shared__ float imgn_lds[96][TS];
  __shared__ float pf_lds[96][TS];

  const int blk = blockIdx.x;            // B * (SS/TS) = 256 blocks
  const int b = blk / (SS / TS);
  const int s0 = (blk % (SS / TS)) * TS;
  const int tid = threadIdx.x;

  for (int i = tid; i < 64 * TS; i += 256) {
    int c = i / TS, s = i % TS;
    x_lds[c][s] = imgf[((size_t)b * 64 + c) * SS + s0 + s];
  }
  for (int i = tid; i < 96 * TS; i += 256) {
    int c = i / TS, s = i % TS;
    pf_lds[c][s] = pf[((size_t)b * 96 + c) * SS + s0 + s];
  }
  __syncthreads();

  for (int i = tid; i < 96 * TS; i += 256) {
    int oc = i / TS, s = i % TS;
    float a = b_img[oc];
#pragma unroll
    for (int c = 0; c < 64; ++c) a = fmaf(w_img[oc * 64 + c], x_lds[c][s], a);
    img_lds[oc][s] = fmaxf(a, 0.f);
  }
  __syncthreads();

  for (int i = tid; i < 24 * TS; i += 256) {
    int r = i / TS, s = i % TS;
    float a = b_fc2[r];
#pragma unroll
    for (int c = 0; c < 96; ++c) a = fmaf(w_fc2[r * 96 + c], img_lds[c][s], a);
    ri_lds[r][s] = tanhf(a);
  }
  __syncthreads();

  if (tid < TS) {
    float a = b_fc3[0];
#pragma unroll
    for (int r = 0; r < 24; ++r) a = fmaf(w_fc3[r], ri_lds[r][tid], a);
    att_lds[tid] = 1.f / (1.f + expf(-a));
  }
  __syncthreads();

  for (int i = tid; i < 96 * TS; i += 256) {
    int c = i / TS, s = i % TS;
    float v = img_lds[c][s];
    img_lds[c][s] = fmaf(v, att_lds[s], v);
  }
  __syncthreads();

  for (int i = tid; i < 96 * TS; i += 256) {
    int oc = i / TS, s = i % TS;
    float a = b_pc[oc];
#pragma unroll
    for (int c = 0; c < 96; ++c) a = fmaf(w_pc[oc * 96 + c], img_lds[c][s], a);
    imgn_lds[oc][s] = fmaxf(a, 0.f);
  }
  __syncthreads();

  for (int i = tid; i < 128 * TS; i += 256) {
    int oc = i / TS, s = i % TS;
    float a = b_fuse[oc];
#pragma unroll
    for (int c = 0; c < 96; ++c) a = fmaf(w_fuse[oc * 192 + c], pf_lds[c][s], a);
#pragma unroll
    for (int c = 0; c < 96; ++c) a = fmaf(w_fuse[oc * 192 + 96 + c], imgn_lds[c][s], a);
    out[((size_t)b * 128 + oc) * SS + s0 + s] = fmaxf(a, 0.f);
  }
}

// ---------------------------------------------------------------------------
extern "C" void kernel_launch(void* const* d_in, const int* in_sizes, int n_in,
                              void* d_out, int out_size, void* d_ws, size_t ws_size,
                              hipStream_t stream)
{
  const float* xyz    = (const float*)d_in[0];
  const float* feat   = (const float*)d_in[1];
  const float* imgf   = (const float*)d_in[2];
  const float* w0_0   = (const float*)d_in[3];
  const float* b0_0   = (const float*)d_in[4];
  const float* w0_1   = (const float*)d_in[5];
  const float* b0_1   = (const float*)d_in[6];
  const float* w0_2   = (const float*)d_in[7];
  const float* b0_2   = (const float*)d_in[8];
  const float* w1_0   = (const float*)d_in[9];
  const float* b1_0   = (const float*)d_in[10];
  const float* w1_1   = (const float*)d_in[11];
  const float* b1_1   = (const float*)d_in[12];
  const float* w1_2   = (const float*)d_in[13];
  const float* b1_2   = (const float*)d_in[14];
  const float* w_img  = (const float*)d_in[15];
  const float* b_img  = (const float*)d_in[16];
  const float* w_fc2  = (const float*)d_in[17];
  const float* b_fc2  = (const float*)d_in[18];
  const float* w_fc3  = (const float*)d_in[19];
  const float* b_fc3  = (const float*)d_in[20];
  const float* w_pc   = (const float*)d_in[21];
  const float* b_pc   = (const float*)d_in[22];
  const float* w_fuse = (const float*)d_in[23];
  const float* b_fuse = (const float*)d_in[24];
  float* out = (float*)d_out;

  float4* spts = (float4*)d_ws;                          // B*N float4
  float4* x4   = spts + (size_t)BB * NN;                 // B*N float4
  float*  nxyz = (float*)(x4 + (size_t)BB * NN);         // B*S*3 f32
  int*    idx0 = (int*)(nxyz + (size_t)BB * SS * 3);     // B*S*16 i32
  int*    idx1 = idx0 + (size_t)BB * SS * 16;            // B*S*32 i32
  float*  pf   = (float*)(idx1 + (size_t)BB * SS * 32);  // B*96*S f32

  sort_kernel<<<BB, 1024, 0, stream>>>(xyz, spts, x4);
  fps_kernel<<<BB, 1024, 0, stream>>>(x4, spts, nxyz);
  ballq_kernel<16><<<BB * SS / 4, 256, 0, stream>>>(xyz, nxyz, idx0, 0.25f);
  ballq_kernel<32><<<BB * SS / 4, 256, 0, stream>>>(xyz, nxyz, idx1, 1.0f);
  group_mlp_kernel<16, 16, 16, 32><<<BB * SS / 16, 256, 0, stream>>>(
      xyz, feat, nxyz, idx0, w0_0, b0_0, w0_1, b0_1, w0_2, b0_2, pf, 0);
  group_mlp_kernel<32, 32, 32, 64><<<BB * SS / 8, 256, 0, stream>>>(
      xyz, feat, nxyz, idx1, w1_0, b1_0, w1_1, b1_1, w1_2, b1_2, pf, 32);
  img_fuse_kernel<<<BB * SS / 32, 256, 0, stream>>>(
      imgf, pf, w_img, b_img, w_fc2, b_fc2, w_fc3, b_fc3, w_pc, b_pc,
      w_fuse, b_fuse, out);
}